// Round 6
// baseline (139.195 us; speedup 1.0000x reference)
//
#include <hip/hip_runtime.h>
#include <cstddef>

#define EPS 1e-5f

constexpr int NG  = 8192;   // genes
constexpr int HID = 32768;  // hidden (= NG*4)
constexpr int NTF = 1024;   // TFs
constexpr int B   = 256;    // batch

// round-to-nearest-even f32 -> bf16 bits (no NaN inputs in this problem)
static __device__ __forceinline__ unsigned short f2bf(float v) {
    union { float f; unsigned u; } a; a.f = v;
    unsigned r = a.u + 0x7fffu + ((a.u >> 16) & 1u);
    return (unsigned short)(r >> 16);
}
static __device__ __forceinline__ float bf2f(unsigned short b) {
    union { unsigned u; float f; } a; a.u = (unsigned)b << 16;
    return a.f;
}

// ---------------------------------------------------------------------------
// K1: stats + fold. Computes BN1 (m1, inv1) and BN2 (inv2) per column on the
// bf16(x) pipeline (so K2's recompute matches the stats EXACTLY), folds BN1
// into per-gene constant records, and writes xT = bf16(x) transposed [NG][B].
// NO h2 materialization — layer 3 recomputes from x instead (4x fewer gather
// bytes: one x column instead of four h2 columns per (TF, gene) edge).
//
// Record gconst[g][32]: [0:4)=w1, [4:8)=b1, [8:24)=w2*inv1 (out-col major),
// [24:28)=b2 - sum(w2*inv1*m1), [28:32) pad.
// Block = 64 columns (16 genes) x 4 batch-slices of 64 rows.
// ---------------------------------------------------------------------------
__global__ __launch_bounds__(256) void stats12(
    const float* __restrict__ x,   // [B][NG]
    const float* __restrict__ w1,  // [HID]
    const float* __restrict__ b1,  // [HID]
    const float* __restrict__ w2,  // [HID*4]
    const float* __restrict__ b2,  // [HID]
    unsigned short* __restrict__ xTb, // [NG][B] bf16 bits
    float* __restrict__ gconst,       // [NG][32]
    float* __restrict__ inv2g)        // [HID]
{
    const int lane  = threadIdx.x & 63;   // column within block tile
    const int slice = threadIdx.x >> 6;   // 64-row batch slice
    const int c     = (blockIdx.x << 6) + lane;  // global hidden column
    const int g     = c >> 2;             // gene
    const int b0    = slice << 6;

    __shared__ float redA[4][64], redB[4][64];
    __shared__ float m1s[64], inv1s[64];
    __shared__ unsigned short xt[16][258];   // padded: conflict-free writes

    const float w1c = w1[c], b1c = b1[c];
    const float* xp = x + (size_t)b0 * NG + g;

    // ---- phase A: bf16-round x into tile; BN1 stats on bf16(x) ----
    float s = 0.f, s2 = 0.f;
    #pragma unroll 8
    for (int i = 0; i < 64; ++i) {
        float v = xp[(size_t)i * NG];
        unsigned short vb = f2bf(v);
        if ((lane & 3) == 0) xt[lane >> 2][b0 + i] = vb;
        float h = fmaxf(fmaf(w1c, bf2f(vb), b1c), 0.f);
        s += h;
        s2 = fmaf(h, h, s2);
    }
    redA[slice][lane] = s;
    redB[slice][lane] = s2;
    __syncthreads();
    if (slice == 0) {
        float S  = redA[0][lane] + redA[1][lane] + redA[2][lane] + redA[3][lane];
        float S2 = redB[0][lane] + redB[1][lane] + redB[2][lane] + redB[3][lane];
        float m  = S * (1.f / 256.f);
        float v  = fmaf(-m, m, S2 * (1.f / 256.f));
        m1s[lane]   = m;
        inv1s[lane] = rsqrtf(v + EPS);
    }
    __syncthreads();

    // ---- fold BN1 into the 4x4 block weights (all threads need them) ----
    const int lbase = lane & ~3;
    const int gbase = g << 2;
    float w1j[4], b1j[4], w2s[4];
    float bconst = b2[c];
    #pragma unroll
    for (int j = 0; j < 4; ++j) {
        w1j[j] = w1[gbase + j];
        b1j[j] = b1[gbase + j];
        float wv = w2[(c << 2) + j] * inv1s[lbase + j];
        w2s[j] = wv;
        bconst = fmaf(-wv, m1s[lbase + j], bconst);
    }

    // ---- write per-gene constant records (slice 0 only; no duplicates) ----
    if (slice == 0) {
        float* rec = gconst + ((size_t)g << 5);
        const int q = c & 3;
        #pragma unroll
        for (int k = 0; k < 4; ++k) rec[8 + (q << 2) + k] = w2s[k];
        rec[24 + q] = bconst;
        if (q == 0) {
            #pragma unroll
            for (int k = 0; k < 4; ++k) { rec[k] = w1j[k]; rec[4 + k] = b1j[k]; }
        }
    }

    // ---- flush xT tile: 16 genes x 256 rows, coalesced 512-B runs ----
    #pragma unroll 4
    for (int k = 0; k < 16; ++k)
        xTb[((size_t)blockIdx.x << 12) + (k << 8) + threadIdx.x] = xt[k][threadIdx.x];

    // ---- phase B: recompute h2 from bf16(x) in LDS, BN2 stats only ----
    float t2s = 0.f, t2s2 = 0.f;
    const int gl = lane >> 2;
    #pragma unroll 8
    for (int i = 0; i < 64; ++i) {
        float vv = bf2f(xt[gl][b0 + i]);
        float acc = bconst;
        #pragma unroll
        for (int j = 0; j < 4; ++j) {
            float r = fmaxf(fmaf(w1j[j], vv, b1j[j]), 0.f);
            acc = fmaf(w2s[j], r, acc);
        }
        float r2 = fmaxf(acc, 0.f);
        t2s += r2;
        t2s2 = fmaf(r2, r2, t2s2);
    }

    __syncthreads();                 // slice0's redA reads (phase A) are done
    redA[slice][lane] = t2s;
    redB[slice][lane] = t2s2;
    __syncthreads();
    if (slice == 0) {
        float S  = redA[0][lane] + redA[1][lane] + redA[2][lane] + redA[3][lane];
        float S2 = redB[0][lane] + redB[1][lane] + redB[2][lane] + redB[3][lane];
        float m  = S * (1.f / 256.f);
        float v  = fmaf(-m, m, S2 * (1.f / 256.f));
        inv2g[c] = rsqrtf(v + EPS);
    }
}

// ---------------------------------------------------------------------------
// K2: layer-3 via recompute-from-x. Block = TF t, thread = batch row r.
// Per gene slot i: gene index + 28-float record come in via WAVE-UNIFORM
// scalar loads (s_load path — off the VALU/vmem critical path); the only
// vector load is one bf16 x value per (gene,row): xT[g][r], 128 B/wave
// coalesced, 4.2 MB working set -> mostly per-XCD-L2 resident.
// BN2 folds into wls (= w3 * inv2); BN2 mean and b3 cancel under BN3's
// mean subtraction. BN3 finishes in-block.
// ---------------------------------------------------------------------------
__global__ __launch_bounds__(256) void tfdot(
    const unsigned short* __restrict__ xTb,  // [NG][B]
    const float* __restrict__ gconst,        // [NG][32]
    const float* __restrict__ inv2g,         // [HID]
    const float* __restrict__ w3,            // [NTF*256]
    const int*   __restrict__ cols3,         // [NTF*256]
    float* __restrict__ out)                 // [B][NTF]
{
    const int t   = blockIdx.x;
    const int tid = threadIdx.x;      // batch row

    __shared__ float wls[256];
    __shared__ float rs[4], rs2[4];

    // fold BN2 invstd into w3 (per edge)
    {
        const int e = (t << 8) + tid;
        wls[tid] = w3[e] * inv2g[cols3[e]];
    }
    __syncthreads();

    float z = 0.f;
    #pragma unroll 2
    for (int i = 0; i < 64; ++i) {
        // gene for slot i: wave-uniform -> scalar load
        int col0 = __builtin_amdgcn_readfirstlane(cols3[(t << 8) + (i << 2)]);
        const int g = col0 >> 2;
        const float* rec = gconst + ((size_t)g << 5);   // uniform -> s_loads

        float xv = bf2f(xTb[(g << 8) + tid]);           // the one vector load

        float h0 = fmaxf(fmaf(rec[0], xv, rec[4]), 0.f);
        float h1 = fmaxf(fmaf(rec[1], xv, rec[5]), 0.f);
        float h2 = fmaxf(fmaf(rec[2], xv, rec[6]), 0.f);
        float h3 = fmaxf(fmaf(rec[3], xv, rec[7]), 0.f);

        const float4 wt = *(const float4*)&wls[i << 2]; // b128 broadcast
        float a0 = rec[24], a1 = rec[25], a2 = rec[26], a3 = rec[27];
        a0 = fmaf(rec[8],  h0, a0); a0 = fmaf(rec[9],  h1, a0);
        a0 = fmaf(rec[10], h2, a0); a0 = fmaf(rec[11], h3, a0);
        a1 = fmaf(rec[12], h0, a1); a1 = fmaf(rec[13], h1, a1);
        a1 = fmaf(rec[14], h2, a1); a1 = fmaf(rec[15], h3, a1);
        a2 = fmaf(rec[16], h0, a2); a2 = fmaf(rec[17], h1, a2);
        a2 = fmaf(rec[18], h2, a2); a2 = fmaf(rec[19], h3, a2);
        a3 = fmaf(rec[20], h0, a3); a3 = fmaf(rec[21], h1, a3);
        a3 = fmaf(rec[22], h2, a3); a3 = fmaf(rec[23], h3, a3);

        z = fmaf(wt.x, fmaxf(a0, 0.f), z);
        z = fmaf(wt.y, fmaxf(a1, 0.f), z);
        z = fmaf(wt.z, fmaxf(a2, 0.f), z);
        z = fmaf(wt.w, fmaxf(a3, 0.f), z);
    }

    // BN3 over the 256 batch rows (per-t constants cancel)
    float s = z, s2 = z * z;
    #pragma unroll
    for (int o = 32; o > 0; o >>= 1) {
        s  += __shfl_xor(s, o);
        s2 += __shfl_xor(s2, o);
    }
    if ((tid & 63) == 0) { rs[tid >> 6] = s; rs2[tid >> 6] = s2; }
    __syncthreads();
    float S  = rs[0] + rs[1] + rs[2] + rs[3];
    float S2 = rs2[0] + rs2[1] + rs2[2] + rs2[3];
    float m  = S * (1.f / 256.f);
    float v  = fmaf(-m, m, S2 * (1.f / 256.f));
    out[(size_t)tid * NTF + t] = (z - m) * rsqrtf(v + EPS);
}

// ---------------------------------------------------------------------------
extern "C" void kernel_launch(void* const* d_in, const int* in_sizes, int n_in,
                              void* d_out, int out_size, void* d_ws, size_t ws_size,
                              hipStream_t stream) {
    const float* x   = (const float*)d_in[0];
    const float* w1  = (const float*)d_in[1];
    const float* b1  = (const float*)d_in[2];
    const float* w2  = (const float*)d_in[3];
    const float* b2  = (const float*)d_in[4];
    const float* w3  = (const float*)d_in[5];
    const float* b3  = (const float*)d_in[6];  (void)b3;  // cancels in BN3
    const int* cols3 = (const int*)d_in[12];
    float* out = (float*)d_out;

    // workspace: xT bf16 [NG][B] (4.2 MB) + gconst [NG][32] (1 MB) + inv2g
    unsigned short* xTb = (unsigned short*)d_ws;
    float* gconst = (float*)(xTb + (size_t)NG * B);
    float* inv2g  = gconst + (size_t)NG * 32;

    stats12<<<HID / 64, 256, 0, stream>>>(x, w1, b1, w2, b2, xTb, gconst, inv2g);
    tfdot  <<<NTF,      256, 0, stream>>>(xTb, gconst, inv2g, w3, cols3, out);
}

// Round 7
// 128.874 us; speedup vs baseline: 1.0801x; 1.0801x over previous
//
#include <hip/hip_runtime.h>
#include <cstddef>

#define EPS 1e-5f

constexpr int NG  = 8192;   // genes
constexpr int HID = 32768;  // hidden (= NG*4)
constexpr int NTF = 1024;   // TFs
constexpr int B   = 256;    // batch

// round-to-nearest-even f32 -> bf16 bits (no NaN inputs in this problem)
static __device__ __forceinline__ unsigned short f2bf(float v) {
    union { float f; unsigned u; } a; a.f = v;
    unsigned r = a.u + 0x7fffu + ((a.u >> 16) & 1u);
    return (unsigned short)(r >> 16);
}
static __device__ __forceinline__ float bf2f(unsigned short b) {
    union { unsigned u; float f; } a; a.u = (unsigned)b << 16;
    return a.f;
}

// ---------------------------------------------------------------------------
// K1: stats + fold. Computes BN1 (m1, inv1) and BN2 (inv2) per column on the
// bf16(x) pipeline (so K2's recompute matches the stats EXACTLY), folds BN1
// into per-gene constant records, and writes xT = bf16(x) transposed [NG][B].
// No h2 materialization — layer 3 recomputes from x (4x fewer gather bytes).
//
// Record gconst[g][32]: [0:4)=w1, [4:8)=b1, [8:24)=w2*inv1 (out-col major),
// [24:28)=b2 - sum(w2*inv1*m1), [28:32) pad (stride 32 -> float4-clean).
// Block = 64 columns (16 genes) x 4 batch-slices of 64 rows.
// ---------------------------------------------------------------------------
__global__ __launch_bounds__(256) void stats12(
    const float* __restrict__ x,   // [B][NG]
    const float* __restrict__ w1,  // [HID]
    const float* __restrict__ b1,  // [HID]
    const float* __restrict__ w2,  // [HID*4]
    const float* __restrict__ b2,  // [HID]
    unsigned short* __restrict__ xTb, // [NG][B] bf16 bits
    float* __restrict__ gconst,       // [NG][32]
    float* __restrict__ inv2g)        // [HID]
{
    const int lane  = threadIdx.x & 63;   // column within block tile
    const int slice = threadIdx.x >> 6;   // 64-row batch slice
    const int c     = (blockIdx.x << 6) + lane;  // global hidden column
    const int g     = c >> 2;             // gene
    const int b0    = slice << 6;

    __shared__ float redA[4][64], redB[4][64];
    __shared__ float m1s[64], inv1s[64];
    __shared__ unsigned short xt[16][258];   // padded: conflict-free writes

    const float w1c = w1[c], b1c = b1[c];
    const float* xp = x + (size_t)b0 * NG + g;

    // ---- phase A: bf16-round x into tile; BN1 stats on bf16(x) ----
    float s = 0.f, s2 = 0.f;
    #pragma unroll 8
    for (int i = 0; i < 64; ++i) {
        float v = xp[(size_t)i * NG];
        unsigned short vb = f2bf(v);
        if ((lane & 3) == 0) xt[lane >> 2][b0 + i] = vb;
        float h = fmaxf(fmaf(w1c, bf2f(vb), b1c), 0.f);
        s += h;
        s2 = fmaf(h, h, s2);
    }
    redA[slice][lane] = s;
    redB[slice][lane] = s2;
    __syncthreads();
    if (slice == 0) {
        float S  = redA[0][lane] + redA[1][lane] + redA[2][lane] + redA[3][lane];
        float S2 = redB[0][lane] + redB[1][lane] + redB[2][lane] + redB[3][lane];
        float m  = S * (1.f / 256.f);
        float v  = fmaf(-m, m, S2 * (1.f / 256.f));
        m1s[lane]   = m;
        inv1s[lane] = rsqrtf(v + EPS);
    }
    __syncthreads();

    // ---- fold BN1 into the 4x4 block weights (all threads need them) ----
    const int lbase = lane & ~3;
    const int gbase = g << 2;
    float w1j[4], b1j[4], w2s[4];
    float bconst = b2[c];
    #pragma unroll
    for (int j = 0; j < 4; ++j) {
        w1j[j] = w1[gbase + j];
        b1j[j] = b1[gbase + j];
        float wv = w2[(c << 2) + j] * inv1s[lbase + j];
        w2s[j] = wv;
        bconst = fmaf(-wv, m1s[lbase + j], bconst);
    }

    // ---- write per-gene constant records (slice 0 only; no duplicates) ----
    if (slice == 0) {
        float* rec = gconst + ((size_t)g << 5);
        const int q = c & 3;
        #pragma unroll
        for (int k = 0; k < 4; ++k) rec[8 + (q << 2) + k] = w2s[k];
        rec[24 + q] = bconst;
        if (q == 0) {
            #pragma unroll
            for (int k = 0; k < 4; ++k) { rec[k] = w1j[k]; rec[4 + k] = b1j[k]; }
        }
    }

    // ---- flush xT tile: 16 genes x 256 rows, coalesced 512-B runs ----
    #pragma unroll 4
    for (int k = 0; k < 16; ++k)
        xTb[((size_t)blockIdx.x << 12) + (k << 8) + threadIdx.x] = xt[k][threadIdx.x];

    // ---- phase B: recompute h2 from bf16(x) in LDS, BN2 stats only ----
    float t2s = 0.f, t2s2 = 0.f;
    const int gl = lane >> 2;
    #pragma unroll 8
    for (int i = 0; i < 64; ++i) {
        float vv = bf2f(xt[gl][b0 + i]);
        float acc = bconst;
        #pragma unroll
        for (int j = 0; j < 4; ++j) {
            float r = fmaxf(fmaf(w1j[j], vv, b1j[j]), 0.f);
            acc = fmaf(w2s[j], r, acc);
        }
        float r2 = fmaxf(acc, 0.f);
        t2s += r2;
        t2s2 = fmaf(r2, r2, t2s2);
    }

    __syncthreads();                 // slice0's redA reads (phase A) are done
    redA[slice][lane] = t2s;
    redB[slice][lane] = t2s2;
    __syncthreads();
    if (slice == 0) {
        float S  = redA[0][lane] + redA[1][lane] + redA[2][lane] + redA[3][lane];
        float S2 = redB[0][lane] + redB[1][lane] + redB[2][lane] + redB[3][lane];
        float m  = S * (1.f / 256.f);
        float v  = fmaf(-m, m, S2 * (1.f / 256.f));
        inv2g[c] = rsqrtf(v + EPS);
    }
}

// ---------------------------------------------------------------------------
// K2 v2: layer-3 via recompute-from-x. Block = TF t, thread = batch row r.
// ALL 64 gene records (128 B each) are staged into LDS up-front in 2
// coalesced rounds (R6's killer was a per-iteration dependent s_load chain
// into a 1 MB table -> serial L2 latency). Main loop: LDS broadcasts + one
// independent 2-B xv load per slot (prefetchable), ~34 VALU/slot.
// BN2 folds into wls (= w3 * inv2); BN2 mean and b3 cancel under BN3's
// mean subtraction. BN3 finishes in-block.
// ---------------------------------------------------------------------------
__global__ __launch_bounds__(256) void tfdot(
    const unsigned short* __restrict__ xTb,  // [NG][B]
    const float* __restrict__ gconst,        // [NG][32]
    const float* __restrict__ inv2g,         // [HID]
    const float* __restrict__ w3,            // [NTF*256]
    const int*   __restrict__ cols3,         // [NTF*256]
    float* __restrict__ out)                 // [B][NTF]
{
    const int t   = blockIdx.x;
    const int tid = threadIdx.x;      // batch row

    __shared__ float wls[256];
    __shared__ int   glist[64];
    __shared__ float recs[64][32];    // 8 KB record cache
    __shared__ float rs[4], rs2[4];

    // fold BN2 invstd into w3; extract the 64 gene ids
    {
        const int e   = (t << 8) + tid;
        const int col = cols3[e];
        wls[tid] = w3[e] * inv2g[col];
        if ((tid & 3) == 0) glist[tid >> 2] = col >> 2;
    }
    __syncthreads();

    // stage 64 records: 8 threads/record x float4, 2 rounds, coalesced 128 B
    {
        const int q  = tid & 7;
        const int s0 = tid >> 3;          // 0..31
        const float4* g4 = (const float4*)gconst;
        ((float4*)&recs[s0][0])[q]      = g4[((size_t)glist[s0] << 3) + q];
        ((float4*)&recs[s0 + 32][0])[q] = g4[((size_t)glist[s0 + 32] << 3) + q];
    }
    __syncthreads();

    float z = 0.f;
    #pragma unroll 4
    for (int i = 0; i < 64; ++i) {
        const int g = glist[i];
        float xv = bf2f(xTb[(g << 8) + tid]);          // the one vector load

        const float4 w1v = *(const float4*)&recs[i][0];
        const float4 b1v = *(const float4*)&recs[i][4];
        const float4 rC  = *(const float4*)&recs[i][8];
        const float4 rD  = *(const float4*)&recs[i][12];
        const float4 rE  = *(const float4*)&recs[i][16];
        const float4 rF  = *(const float4*)&recs[i][20];
        const float4 bc  = *(const float4*)&recs[i][24];
        const float4 wt  = *(const float4*)&wls[i << 2];

        float h0 = fmaxf(fmaf(w1v.x, xv, b1v.x), 0.f);
        float h1 = fmaxf(fmaf(w1v.y, xv, b1v.y), 0.f);
        float h2 = fmaxf(fmaf(w1v.z, xv, b1v.z), 0.f);
        float h3 = fmaxf(fmaf(w1v.w, xv, b1v.w), 0.f);

        float a0 = bc.x, a1 = bc.y, a2 = bc.z, a3 = bc.w;
        a0 = fmaf(rC.x, h0, a0); a0 = fmaf(rC.y, h1, a0);
        a0 = fmaf(rC.z, h2, a0); a0 = fmaf(rC.w, h3, a0);
        a1 = fmaf(rD.x, h0, a1); a1 = fmaf(rD.y, h1, a1);
        a1 = fmaf(rD.z, h2, a1); a1 = fmaf(rD.w, h3, a1);
        a2 = fmaf(rE.x, h0, a2); a2 = fmaf(rE.y, h1, a2);
        a2 = fmaf(rE.z, h2, a2); a2 = fmaf(rE.w, h3, a2);
        a3 = fmaf(rF.x, h0, a3); a3 = fmaf(rF.y, h1, a3);
        a3 = fmaf(rF.z, h2, a3); a3 = fmaf(rF.w, h3, a3);

        z = fmaf(wt.x, fmaxf(a0, 0.f), z);
        z = fmaf(wt.y, fmaxf(a1, 0.f), z);
        z = fmaf(wt.z, fmaxf(a2, 0.f), z);
        z = fmaf(wt.w, fmaxf(a3, 0.f), z);
    }

    // BN3 over the 256 batch rows (per-t constants cancel)
    float s = z, s2 = z * z;
    #pragma unroll
    for (int o = 32; o > 0; o >>= 1) {
        s  += __shfl_xor(s, o);
        s2 += __shfl_xor(s2, o);
    }
    if ((tid & 63) == 0) { rs[tid >> 6] = s; rs2[tid >> 6] = s2; }
    __syncthreads();
    float S  = rs[0] + rs[1] + rs[2] + rs[3];
    float S2 = rs2[0] + rs2[1] + rs2[2] + rs2[3];
    float m  = S * (1.f / 256.f);
    float v  = fmaf(-m, m, S2 * (1.f / 256.f));
    out[(size_t)tid * NTF + t] = (z - m) * rsqrtf(v + EPS);
}

// ---------------------------------------------------------------------------
extern "C" void kernel_launch(void* const* d_in, const int* in_sizes, int n_in,
                              void* d_out, int out_size, void* d_ws, size_t ws_size,
                              hipStream_t stream) {
    const float* x   = (const float*)d_in[0];
    const float* w1  = (const float*)d_in[1];
    const float* b1  = (const float*)d_in[2];
    const float* w2  = (const float*)d_in[3];
    const float* b2  = (const float*)d_in[4];
    const float* w3  = (const float*)d_in[5];
    const float* b3  = (const float*)d_in[6];  (void)b3;  // cancels in BN3
    const int* cols3 = (const int*)d_in[12];
    float* out = (float*)d_out;

    // workspace: xT bf16 [NG][B] (4.2 MB) + gconst [NG][32] (1 MB) + inv2g
    unsigned short* xTb = (unsigned short*)d_ws;
    float* gconst = (float*)(xTb + (size_t)NG * B);
    float* inv2g  = gconst + (size_t)NG * 32;

    stats12<<<HID / 64, 256, 0, stream>>>(x, w1, b1, w2, b2, xTb, gconst, inv2g);
    tfdot  <<<NTF,      256, 0, stream>>>(xTb, gconst, inv2g, w3, cols3, out);
}

// Round 8
// 124.729 us; speedup vs baseline: 1.1160x; 1.0332x over previous
//
#include <hip/hip_runtime.h>
#include <cstddef>

#define EPS 1e-5f

constexpr int NG  = 8192;   // genes
constexpr int HID = 32768;  // hidden (= NG*4)
constexpr int NTF = 1024;   // TFs
constexpr int B   = 256;    // batch

// round-to-nearest-even f32 -> bf16 bits (no NaN inputs in this problem)
static __device__ __forceinline__ unsigned short f2bf(float v) {
    union { float f; unsigned u; } a; a.f = v;
    unsigned r = a.u + 0x7fffu + ((a.u >> 16) & 1u);
    return (unsigned short)(r >> 16);
}
static __device__ __forceinline__ float bf2f(unsigned short b) {
    union { unsigned u; float f; } a; a.u = (unsigned)b << 16;
    return a.f;
}

// ---------------------------------------------------------------------------
// K1: stats + fold. Computes BN1 (m1, inv1) and BN2 (inv2) per column on the
// bf16(x) pipeline (so K2's recompute matches the stats EXACTLY), folds BN1
// into per-gene constant records, and writes xT = bf16(x) transposed [NG][B].
// No h2 materialization — layer 3 recomputes from x (4x fewer gather bytes).
//
// Record gconst[g][32]: [0:4)=w1, [4:8)=b1, [8:24)=w2*inv1 (out-col major),
// [24:28)=b2 - sum(w2*inv1*m1), [28:32) pad (stride 32 -> float4-clean).
// Block = 64 columns (16 genes) x 4 batch-slices of 64 rows.
// ---------------------------------------------------------------------------
__global__ __launch_bounds__(256) void stats12(
    const float* __restrict__ x,   // [B][NG]
    const float* __restrict__ w1,  // [HID]
    const float* __restrict__ b1,  // [HID]
    const float* __restrict__ w2,  // [HID*4]
    const float* __restrict__ b2,  // [HID]
    unsigned short* __restrict__ xTb, // [NG][B] bf16 bits
    float* __restrict__ gconst,       // [NG][32]
    float* __restrict__ inv2g)        // [HID]
{
    const int lane  = threadIdx.x & 63;   // column within block tile
    const int slice = threadIdx.x >> 6;   // 64-row batch slice
    const int c     = (blockIdx.x << 6) + lane;  // global hidden column
    const int g     = c >> 2;             // gene
    const int b0    = slice << 6;

    __shared__ float redA[4][64], redB[4][64];
    __shared__ float m1s[64], inv1s[64];
    __shared__ unsigned short xt[16][258];   // padded: conflict-free writes

    const float w1c = w1[c], b1c = b1[c];
    const float* xp = x + (size_t)b0 * NG + g;

    // ---- phase A: bf16-round x into tile; BN1 stats on bf16(x) ----
    float s = 0.f, s2 = 0.f;
    #pragma unroll 8
    for (int i = 0; i < 64; ++i) {
        float v = xp[(size_t)i * NG];
        unsigned short vb = f2bf(v);
        if ((lane & 3) == 0) xt[lane >> 2][b0 + i] = vb;
        float h = fmaxf(fmaf(w1c, bf2f(vb), b1c), 0.f);
        s += h;
        s2 = fmaf(h, h, s2);
    }
    redA[slice][lane] = s;
    redB[slice][lane] = s2;
    __syncthreads();
    if (slice == 0) {
        float S  = redA[0][lane] + redA[1][lane] + redA[2][lane] + redA[3][lane];
        float S2 = redB[0][lane] + redB[1][lane] + redB[2][lane] + redB[3][lane];
        float m  = S * (1.f / 256.f);
        float v  = fmaf(-m, m, S2 * (1.f / 256.f));
        m1s[lane]   = m;
        inv1s[lane] = rsqrtf(v + EPS);
    }
    __syncthreads();

    // ---- fold BN1 into the 4x4 block weights (all threads need them) ----
    const int lbase = lane & ~3;
    const int gbase = g << 2;
    float w1j[4], b1j[4], w2s[4];
    float bconst = b2[c];
    #pragma unroll
    for (int j = 0; j < 4; ++j) {
        w1j[j] = w1[gbase + j];
        b1j[j] = b1[gbase + j];
        float wv = w2[(c << 2) + j] * inv1s[lbase + j];
        w2s[j] = wv;
        bconst = fmaf(-wv, m1s[lbase + j], bconst);
    }

    // ---- write per-gene constant records (slice 0 only; no duplicates) ----
    if (slice == 0) {
        float* rec = gconst + ((size_t)g << 5);
        const int q = c & 3;
        #pragma unroll
        for (int k = 0; k < 4; ++k) rec[8 + (q << 2) + k] = w2s[k];
        rec[24 + q] = bconst;
        if (q == 0) {
            #pragma unroll
            for (int k = 0; k < 4; ++k) { rec[k] = w1j[k]; rec[4 + k] = b1j[k]; }
        }
    }

    // ---- flush xT tile: 16 genes x 256 rows, coalesced 512-B runs ----
    #pragma unroll 4
    for (int k = 0; k < 16; ++k)
        xTb[((size_t)blockIdx.x << 12) + (k << 8) + threadIdx.x] = xt[k][threadIdx.x];

    // ---- phase B: recompute h2 from bf16(x) in LDS, BN2 stats only ----
    float t2s = 0.f, t2s2 = 0.f;
    const int gl = lane >> 2;
    #pragma unroll 8
    for (int i = 0; i < 64; ++i) {
        float vv = bf2f(xt[gl][b0 + i]);
        float acc = bconst;
        #pragma unroll
        for (int j = 0; j < 4; ++j) {
            float r = fmaxf(fmaf(w1j[j], vv, b1j[j]), 0.f);
            acc = fmaf(w2s[j], r, acc);
        }
        float r2 = fmaxf(acc, 0.f);
        t2s += r2;
        t2s2 = fmaf(r2, r2, t2s2);
    }

    __syncthreads();                 // slice0's redA reads (phase A) are done
    redA[slice][lane] = t2s;
    redB[slice][lane] = t2s2;
    __syncthreads();
    if (slice == 0) {
        float S  = redA[0][lane] + redA[1][lane] + redA[2][lane] + redA[3][lane];
        float S2 = redB[0][lane] + redB[1][lane] + redB[2][lane] + redB[3][lane];
        float m  = S * (1.f / 256.f);
        float v  = fmaf(-m, m, S2 * (1.f / 256.f));
        inv2g[c] = rsqrtf(v + EPS);
    }
}

// ---------------------------------------------------------------------------
// K2 v3: layer-3 via recompute-from-x. Block = TF t.
// Wave = slot-QUARTER (16 of the 64 gene slots), lane = row-QUAD (4 batch
// rows) -> each 128-B record broadcast feeds 4 rows of FMAs (R7 was 1 row:
// LDS-issue-bound at 8192 b128/CU ~= 41 us; this is 2048 ~= 10 us).
// xv loads are uint2 = 4 packed bf16 rows, 512 B/wave contiguous.
// Quarter-partials combine via LDS; BN3 finishes in-block (per-t constants
// cancel under BN3's mean subtraction).
// ---------------------------------------------------------------------------
__global__ __launch_bounds__(256) void tfdot(
    const unsigned short* __restrict__ xTb,  // [NG][B]
    const float* __restrict__ gconst,        // [NG][32]
    const float* __restrict__ inv2g,         // [HID]
    const float* __restrict__ w3,            // [NTF*256]
    const int*   __restrict__ cols3,         // [NTF*256]
    float* __restrict__ out)                 // [B][NTF]
{
    const int t   = blockIdx.x;
    const int tid = threadIdx.x;
    const int eq  = tid >> 6;     // slot quarter (= wave)
    const int rq  = tid & 63;     // row quad: rows 4rq..4rq+3

    __shared__ float wls[256];
    __shared__ int   glist[64];
    __shared__ float recs[64][32];    // 8 KB record cache
    __shared__ float sred[4][260];    // padded quarter-partials
    __shared__ float rs[4], rs2[4];

    // fold BN2 invstd into w3; extract the 64 gene ids
    {
        const int e   = (t << 8) + tid;
        const int col = cols3[e];
        wls[tid] = w3[e] * inv2g[col];
        if ((tid & 3) == 0) glist[tid >> 2] = col >> 2;
    }
    __syncthreads();

    // stage 64 records: 8 threads/record x float4, 2 rounds, coalesced 128 B
    {
        const int q  = tid & 7;
        const int s0 = tid >> 3;          // 0..31
        const float4* g4 = (const float4*)gconst;
        ((float4*)&recs[s0][0])[q]      = g4[((size_t)glist[s0] << 3) + q];
        ((float4*)&recs[s0 + 32][0])[q] = g4[((size_t)glist[s0 + 32] << 3) + q];
    }
    __syncthreads();

    float z0 = 0.f, z1 = 0.f, z2 = 0.f, z3 = 0.f;
    #pragma unroll 4
    for (int k = 0; k < 16; ++k) {
        const int i = (eq << 4) + k;               // my slot
        const int g = glist[i];
        // 4 rows of bf16(x): 8 B/lane, 512 B/wave contiguous
        uint2 u = *(const uint2*)(xTb + (g << 8) + (rq << 2));
        union { unsigned v; float f; } p0, p1, p2, p3;
        p0.v = u.x << 16; p1.v = u.x & 0xffff0000u;
        p2.v = u.y << 16; p3.v = u.y & 0xffff0000u;

        const float4 w1v = *(const float4*)&recs[i][0];
        const float4 b1v = *(const float4*)&recs[i][4];
        const float4 rC  = *(const float4*)&recs[i][8];
        const float4 rD  = *(const float4*)&recs[i][12];
        const float4 rE  = *(const float4*)&recs[i][16];
        const float4 rF  = *(const float4*)&recs[i][20];
        const float4 bc  = *(const float4*)&recs[i][24];
        const float4 wt  = *(const float4*)&wls[i << 2];

        #pragma unroll
        for (int r = 0; r < 4; ++r) {
            const float xv = (r == 0) ? p0.f : (r == 1) ? p1.f : (r == 2) ? p2.f : p3.f;
            float h0 = fmaxf(fmaf(w1v.x, xv, b1v.x), 0.f);
            float h1 = fmaxf(fmaf(w1v.y, xv, b1v.y), 0.f);
            float h2 = fmaxf(fmaf(w1v.z, xv, b1v.z), 0.f);
            float h3 = fmaxf(fmaf(w1v.w, xv, b1v.w), 0.f);

            float a0 = bc.x, a1 = bc.y, a2 = bc.z, a3 = bc.w;
            a0 = fmaf(rC.x, h0, a0); a0 = fmaf(rC.y, h1, a0);
            a0 = fmaf(rC.z, h2, a0); a0 = fmaf(rC.w, h3, a0);
            a1 = fmaf(rD.x, h0, a1); a1 = fmaf(rD.y, h1, a1);
            a1 = fmaf(rD.z, h2, a1); a1 = fmaf(rD.w, h3, a1);
            a2 = fmaf(rE.x, h0, a2); a2 = fmaf(rE.y, h1, a2);
            a2 = fmaf(rE.z, h2, a2); a2 = fmaf(rE.w, h3, a2);
            a3 = fmaf(rF.x, h0, a3); a3 = fmaf(rF.y, h1, a3);
            a3 = fmaf(rF.z, h2, a3); a3 = fmaf(rF.w, h3, a3);

            float zi = wt.x * fmaxf(a0, 0.f);
            zi = fmaf(wt.y, fmaxf(a1, 0.f), zi);
            zi = fmaf(wt.z, fmaxf(a2, 0.f), zi);
            zi = fmaf(wt.w, fmaxf(a3, 0.f), zi);
            if (r == 0) z0 += zi; else if (r == 1) z1 += zi;
            else if (r == 2) z2 += zi; else z3 += zi;
        }
    }
    *(float4*)&sred[eq][rq << 2] = make_float4(z0, z1, z2, z3);
    __syncthreads();

    // combine quarters; BN3 over the 256 batch rows (tid = batch row now)
    float z = sred[0][tid] + sred[1][tid] + sred[2][tid] + sred[3][tid];

    float s = z, s2 = z * z;
    #pragma unroll
    for (int o = 32; o > 0; o >>= 1) {
        s  += __shfl_xor(s, o);
        s2 += __shfl_xor(s2, o);
    }
    if ((tid & 63) == 0) { rs[tid >> 6] = s; rs2[tid >> 6] = s2; }
    __syncthreads();
    float S  = rs[0] + rs[1] + rs[2] + rs[3];
    float S2 = rs2[0] + rs2[1] + rs2[2] + rs2[3];
    float m  = S * (1.f / 256.f);
    float v  = fmaf(-m, m, S2 * (1.f / 256.f));
    out[(size_t)tid * NTF + t] = (z - m) * rsqrtf(v + EPS);
}

// ---------------------------------------------------------------------------
extern "C" void kernel_launch(void* const* d_in, const int* in_sizes, int n_in,
                              void* d_out, int out_size, void* d_ws, size_t ws_size,
                              hipStream_t stream) {
    const float* x   = (const float*)d_in[0];
    const float* w1  = (const float*)d_in[1];
    const float* b1  = (const float*)d_in[2];
    const float* w2  = (const float*)d_in[3];
    const float* b2  = (const float*)d_in[4];
    const float* w3  = (const float*)d_in[5];
    const float* b3  = (const float*)d_in[6];  (void)b3;  // cancels in BN3
    const int* cols3 = (const int*)d_in[12];
    float* out = (float*)d_out;

    // workspace: xT bf16 [NG][B] (4.2 MB) + gconst [NG][32] (1 MB) + inv2g
    unsigned short* xTb = (unsigned short*)d_ws;
    float* gconst = (float*)(xTb + (size_t)NG * B);
    float* inv2g  = gconst + (size_t)NG * 32;

    stats12<<<HID / 64, 256, 0, stream>>>(x, w1, b1, w2, b2, xTb, gconst, inv2g);
    tfdot  <<<NTF,      256, 0, stream>>>(xTb, gconst, inv2g, w3, cols3, out);
}